// Round 1
// baseline (1704.194 us; speedup 1.0000x reference)
//
#include <hip/hip_runtime.h>

// GCN 2-hop propagation for NettackSurrogate.
// Inputs: edge_index (2,E) int32; x (N,128) f32; W (128,64) f32. Output (N,64) f32.

__global__ __launch_bounds__(256) void k_init_deg(float* deg, int n) {
  int i = blockIdx.x * 256 + threadIdx.x;
  if (i < n) deg[i] = 1.0f;
}

__global__ __launch_bounds__(256) void k_count(const int* __restrict__ rows,
                                               const int* __restrict__ cols,
                                               float* deg, int E) {
  int e = blockIdx.x * 256 + threadIdx.x;
  if (e < E) {
    int r = rows[e], c = cols[e];
    if (r != c) atomicAdd(&deg[r], 1.0f);
  }
}

// In-place: buffer holds deg on entry, self_norm (=1/deg) on exit; dis = rsqrt(deg).
__global__ __launch_bounds__(256) void k_norm(float* deg_selfn, float* dis, int n) {
  int i = blockIdx.x * 256 + threadIdx.x;
  if (i < n) {
    float d = deg_selfn[i];
    dis[i] = rsqrtf(d);
    deg_selfn[i] = 1.0f / d;
  }
}

// h = x @ W.  W (128x64 f32 = 32KB) staged in LDS; 4 rows per 256-thread block,
// lane (t&63) = output feature -> LDS reads stride-1 across the wave (conflict-free),
// x row loads are wave-uniform broadcasts.
__global__ __launch_bounds__(256) void k_gemm(const float* __restrict__ x,
                                              const float* __restrict__ W,
                                              float* __restrict__ h, int n) {
  __shared__ float Ws[128 * 64];
  for (int i = threadIdx.x; i < 128 * 64; i += 256) Ws[i] = W[i];
  __syncthreads();
  int row = blockIdx.x * 4 + (threadIdx.x >> 6);
  if (row >= n) return;
  int f = threadIdx.x & 63;
  const float* xr = x + (size_t)row * 128;
  float acc = 0.0f;
#pragma unroll
  for (int k = 0; k < 128; k += 4) {
    float4 xv = *reinterpret_cast<const float4*>(xr + k);
    acc += xv.x * Ws[(k + 0) * 64 + f];
    acc += xv.y * Ws[(k + 1) * 64 + f];
    acc += xv.z * Ws[(k + 2) * 64 + f];
    acc += xv.w * Ws[(k + 3) * 64 + f];
  }
  h[(size_t)row * 64 + f] = acc;
}

// y[i,f] = self_norm[i] * h[i,f]   (initializes the accumulator buffer)
__global__ __launch_bounds__(256) void k_selfinit(const float* __restrict__ selfn,
                                                  const float* __restrict__ hin,
                                                  float* __restrict__ yout, int total) {
  int idx = blockIdx.x * 256 + threadIdx.x;
  if (idx < total) yout[idx] = selfn[idx >> 6] * hin[idx];
}

// Scatter-atomic SPMM: one work-item per (edge, feature).
// 64 consecutive lanes share one edge -> row/col/dis loads broadcast,
// h gather and y atomics are 256B contiguous per edge.
__global__ __launch_bounds__(256) void k_edges(const int* __restrict__ rows,
                                               const int* __restrict__ cols,
                                               const float* __restrict__ dis,
                                               const float* __restrict__ hin,
                                               float* __restrict__ yout, int E) {
  int idx = blockIdx.x * 256 + threadIdx.x;
  int e = idx >> 6;
  if (e < E) {
    int r = rows[e], c = cols[e];
    if (r != c) {
      int f = idx & 63;
      float nrm = dis[r] * dis[c];
      atomicAdd(&yout[(size_t)r * 64 + f], nrm * hin[(size_t)c * 64 + f]);
    }
  }
}

extern "C" void kernel_launch(void* const* d_in, const int* in_sizes, int n_in,
                              void* d_out, int out_size, void* d_ws, size_t ws_size,
                              hipStream_t stream) {
  const int* edge = (const int*)d_in[0];
  const float* x = (const float*)d_in[1];
  const float* W = (const float*)d_in[2];
  float* out = (float*)d_out;

  int E = in_sizes[0] / 2;
  int N = in_sizes[1] / 128;
  const int* rows = edge;      // edge_index[0]
  const int* cols = edge + E;  // edge_index[1]

  char* p = (char*)d_ws;
  auto alloc = [&](size_t bytes) {
    char* q = p;
    p += (bytes + 255) & ~(size_t)255;
    return q;
  };
  float* selfn = (float*)alloc((size_t)N * 4);        // deg -> self_norm
  float* dis   = (float*)alloc((size_t)N * 4);        // rsqrt(deg)
  float* h     = (float*)alloc((size_t)N * 64 * 4);   // x@W
  float* y1    = (float*)alloc((size_t)N * 64 * 4);   // first propagation

  int total = N * 64;
  long ework = (long)E * 64;
  int eblocks = (int)((ework + 255) / 256);

  k_init_deg<<<(N + 255) / 256, 256, 0, stream>>>(selfn, N);
  k_count<<<(E + 255) / 256, 256, 0, stream>>>(rows, cols, selfn, E);
  k_norm<<<(N + 255) / 256, 256, 0, stream>>>(selfn, dis, N);
  k_gemm<<<(N + 3) / 4, 256, 0, stream>>>(x, W, h, N);

  // hop 1: y1 = A_norm @ h
  k_selfinit<<<(total + 255) / 256, 256, 0, stream>>>(selfn, h, y1, total);
  k_edges<<<eblocks, 256, 0, stream>>>(rows, cols, dis, h, y1, E);

  // hop 2: out = A_norm @ y1
  k_selfinit<<<(total + 255) / 256, 256, 0, stream>>>(selfn, y1, out, total);
  k_edges<<<eblocks, 256, 0, stream>>>(rows, cols, dis, y1, out, E);
}

// Round 2
// 761.406 us; speedup vs baseline: 2.2382x; 2.2382x over previous
//
#include <hip/hip_runtime.h>

// GCN 2-hop propagation, CSR-gather formulation (no float atomics).
// Inputs: edge_index (2,E) int32; x (N,128) f32; W (128,64) f32. Output (N,64) f32.
//
// Math: deg[r] = #(non-self edges from r) + 1; dis = rsqrt(deg); selfn = 1/deg.
//   g  = dis * (x@W)                         (pre-scaled features)
//   g1[r]  = selfn[r] * (g[r]  + sum_{r->c, r!=c} g[c])     (= dis * y1)
//   out[r] = dis[r]   * (g1[r] + sum_{r->c, r!=c} g1[c])

__global__ __launch_bounds__(256) void k_zero_i(int* p, int n) {
  int i = blockIdx.x * 256 + threadIdx.x;
  if (i < n) p[i] = 0;
}

__global__ __launch_bounds__(256) void k_count(const int* __restrict__ rows,
                                               const int* __restrict__ cols,
                                               int* __restrict__ deg, int E) {
  int e = blockIdx.x * 256 + threadIdx.x;
  if (e < E) {
    int r = rows[e];
    if (r != cols[e]) atomicAdd(&deg[r], 1);
  }
}

__global__ __launch_bounds__(256) void k_norm(const int* __restrict__ deg,
                                              float* __restrict__ dis,
                                              float* __restrict__ selfn, int n) {
  int i = blockIdx.x * 256 + threadIdx.x;
  if (i < n) {
    float d = (float)deg[i] + 1.0f;
    dis[i] = rsqrtf(d);
    selfn[i] = 1.0f / d;
  }
}

// Per-256-block inclusive scan -> exclusive local scan + block sums.
__global__ __launch_bounds__(256) void k_scan_block(const int* __restrict__ deg,
                                                    int* __restrict__ excl,
                                                    int* __restrict__ bsum, int n) {
  __shared__ int s[256];
  int tid = threadIdx.x;
  int i = blockIdx.x * 256 + tid;
  int v = (i < n) ? deg[i] : 0;
  s[tid] = v;
  __syncthreads();
  for (int off = 1; off < 256; off <<= 1) {
    int t = (tid >= off) ? s[tid - off] : 0;
    __syncthreads();
    s[tid] += t;
    __syncthreads();
  }
  if (i < n) excl[i] = s[tid] - v;
  if (tid == 255) bsum[blockIdx.x] = s[255];
}

// Single-block exclusive scan of block sums (nb <= 1024).
__global__ __launch_bounds__(1024) void k_scan_partials(int* __restrict__ bsum, int nb) {
  __shared__ int s[1024];
  int tid = threadIdx.x;
  int v = (tid < nb) ? bsum[tid] : 0;
  s[tid] = v;
  __syncthreads();
  for (int off = 1; off < 1024; off <<= 1) {
    int t = (tid >= off) ? s[tid - off] : 0;
    __syncthreads();
    s[tid] += t;
    __syncthreads();
  }
  if (tid < nb) bsum[tid] = s[tid] - v;  // exclusive
}

// row_start = local exclusive + scanned block sum; cursor = copy of row_start.
__global__ __launch_bounds__(256) void k_scan_add(int* __restrict__ excl,
                                                  const int* __restrict__ bsum,
                                                  int* __restrict__ cursor, int n) {
  int i = blockIdx.x * 256 + threadIdx.x;
  if (i < n) {
    int v = excl[i] + bsum[blockIdx.x];
    excl[i] = v;
    cursor[i] = v;
  }
}

__global__ __launch_bounds__(256) void k_scatter(const int* __restrict__ rows,
                                                 const int* __restrict__ cols,
                                                 int* __restrict__ cursor,
                                                 int* __restrict__ colidx, int E) {
  int e = blockIdx.x * 256 + threadIdx.x;
  if (e < E) {
    int r = rows[e], c = cols[e];
    if (r != c) {
      int p = atomicAdd(&cursor[r], 1);
      colidx[p] = c;
    }
  }
}

// g = dis * (x @ W).  W (32KB) in LDS; 4 waves x 8 rows = 32 rows per block.
// Lane (t&63) = output feature; LDS reads stride-1 (conflict-free); x loads
// are wave-uniform float4 broadcasts.
__global__ __launch_bounds__(256) void k_gemm_scale(const float* __restrict__ x,
                                                    const float* __restrict__ W,
                                                    const float* __restrict__ dis,
                                                    float* __restrict__ g, int n) {
  __shared__ float Ws[128 * 64];
  for (int i = threadIdx.x; i < 128 * 64; i += 256) Ws[i] = W[i];
  __syncthreads();
  int f = threadIdx.x & 63;
  int base = blockIdx.x * 32 + (threadIdx.x >> 6) * 8;
  for (int rr = 0; rr < 8; ++rr) {
    int row = base + rr;
    if (row >= n) return;
    const float* xr = x + (size_t)row * 128;
    float acc = 0.0f;
#pragma unroll
    for (int k = 0; k < 128; k += 4) {
      float4 xv = *reinterpret_cast<const float4*>(xr + k);
      acc += xv.x * Ws[(k + 0) * 64 + f];
      acc += xv.y * Ws[(k + 1) * 64 + f];
      acc += xv.z * Ws[(k + 2) * 64 + f];
      acc += xv.w * Ws[(k + 3) * 64 + f];
    }
    g[(size_t)row * 64 + f] = dis[row] * acc;
  }
}

// One wave per row: register accumulation over neighbors, one 256B store.
__global__ __launch_bounds__(256) void k_spmm(const int* __restrict__ row_start,
                                              const int* __restrict__ deg,
                                              const int* __restrict__ colidx,
                                              const float* __restrict__ scale,
                                              const float* __restrict__ gin,
                                              float* __restrict__ gout, int n) {
  int f = threadIdx.x & 63;
  int r = blockIdx.x * 4 + (threadIdx.x >> 6);
  if (r >= n) return;
  int start = row_start[r];
  int len = deg[r];
  float acc = gin[(size_t)r * 64 + f];  // self loop
  int j = 0;
  for (; j + 4 <= len; j += 4) {
    int c0 = colidx[start + j + 0];
    int c1 = colidx[start + j + 1];
    int c2 = colidx[start + j + 2];
    int c3 = colidx[start + j + 3];
    float v0 = gin[(size_t)c0 * 64 + f];
    float v1 = gin[(size_t)c1 * 64 + f];
    float v2 = gin[(size_t)c2 * 64 + f];
    float v3 = gin[(size_t)c3 * 64 + f];
    acc += v0 + v1 + v2 + v3;
  }
  for (; j < len; ++j) {
    int c = colidx[start + j];
    acc += gin[(size_t)c * 64 + f];
  }
  gout[(size_t)r * 64 + f] = scale[r] * acc;
}

extern "C" void kernel_launch(void* const* d_in, const int* in_sizes, int n_in,
                              void* d_out, int out_size, void* d_ws, size_t ws_size,
                              hipStream_t stream) {
  const int* edge = (const int*)d_in[0];
  const float* x = (const float*)d_in[1];
  const float* W = (const float*)d_in[2];
  float* out = (float*)d_out;

  int E = in_sizes[0] / 2;
  int N = in_sizes[1] / 128;
  const int* rows = edge;      // edge_index[0]
  const int* cols = edge + E;  // edge_index[1]

  char* p = (char*)d_ws;
  auto alloc = [&](size_t bytes) {
    char* q = p;
    p += (bytes + 255) & ~(size_t)255;
    return q;
  };
  int* deg       = (int*)alloc((size_t)N * 4);
  int* row_start = (int*)alloc((size_t)N * 4);
  int* cursor    = (int*)alloc((size_t)N * 4);
  int* colidx    = (int*)alloc((size_t)E * 4);
  float* dis     = (float*)alloc((size_t)N * 4);
  float* selfn   = (float*)alloc((size_t)N * 4);
  float* g       = (float*)alloc((size_t)N * 64 * 4);
  float* g1      = (float*)alloc((size_t)N * 64 * 4);
  int nblocks = (N + 255) / 256;
  int* bsum      = (int*)alloc((size_t)nblocks * 4);

  // --- CSR build ---
  k_zero_i<<<(N + 255) / 256, 256, 0, stream>>>(deg, N);
  k_count<<<(E + 255) / 256, 256, 0, stream>>>(rows, cols, deg, E);
  k_norm<<<(N + 255) / 256, 256, 0, stream>>>(deg, dis, selfn, N);
  k_scan_block<<<nblocks, 256, 0, stream>>>(deg, row_start, bsum, N);
  k_scan_partials<<<1, 1024, 0, stream>>>(bsum, nblocks);
  k_scan_add<<<nblocks, 256, 0, stream>>>(row_start, bsum, cursor, N);
  k_scatter<<<(E + 255) / 256, 256, 0, stream>>>(rows, cols, cursor, colidx, E);

  // --- feature transform (pre-scaled) ---
  k_gemm_scale<<<(N + 31) / 32, 256, 0, stream>>>(x, W, dis, g, N);

  // --- hop 1: g1 = selfn * (g_self + gather) ---
  k_spmm<<<(N + 3) / 4, 256, 0, stream>>>(row_start, deg, colidx, selfn, g, g1, N);

  // --- hop 2: out = dis * (g1_self + gather) ---
  k_spmm<<<(N + 3) / 4, 256, 0, stream>>>(row_start, deg, colidx, dis, g1, out, N);
}